// Round 10
// baseline (384.402 us; speedup 1.0000x reference)
//
#include <hip/hip_runtime.h>
#include <math.h>

#define NUM_B 1024
#define LW 49
#define CD 384
#define NH 12
#define HD 32
#define SCALE_F 19.595917942265423f   // sqrt(384), faithful to reference

typedef unsigned short u16;
typedef unsigned int u32;
typedef __attribute__((ext_vector_type(8))) short short8;      // 8 bf16
typedef __attribute__((ext_vector_type(8))) _Float16 half8;    // 8 f16
typedef __attribute__((ext_vector_type(4))) float floatx4;

// counted-waitcnt pipeline primitives (T4): barrier WITHOUT vmcnt(0) drain
#define ASM_VMCNT(n) asm volatile("s_waitcnt vmcnt(" #n ")" ::: "memory")
#define ASM_LGKM0()  asm volatile("s_waitcnt lgkmcnt(0)" ::: "memory")
#define BAR()        __builtin_amdgcn_s_barrier()

static __device__ __forceinline__ u16 f2bf(float f) {          // RNE f32->bf16
    unsigned u = __float_as_uint(f);
    u += 0x7fffu + ((u >> 16) & 1u);
    return (u16)(u >> 16);
}
static __device__ __forceinline__ float bf2f(u16 s) {
    return __uint_as_float(((unsigned)s) << 16);
}
static __device__ __forceinline__ u16 f2h_bits(float f) {      // RNE f32->f16 bits
    _Float16 h = (_Float16)f;
    u16 u;
    __builtin_memcpy(&u, &h, 2);
    return u;
}
static __device__ __forceinline__ void gl_lds16(const u16* g, u16* l) {
    __builtin_amdgcn_global_load_lds(
        (const __attribute__((address_space(1))) void*)g,
        (__attribute__((address_space(3))) void*)l, 16, 0, 0);
}

// ---------------------------------------------------------------------------
// Fused prologue (1 launch): x -> bf16 hi/lo; qkv_w -> bf16 hi/lo;
// proj_w -> f16 hi/lo; bm table (bias/mask/pad fused, tn-innermost layout).
// ---------------------------------------------------------------------------
#define X4 4816896     // S/4
#define W4 110592
#define P4 36864
#define BM4 49152
__global__ __launch_bounds__(256) void prep(const float* __restrict__ x,
                                            const float* __restrict__ qkv_w,
                                            const float* __restrict__ proj_w,
                                            const float* __restrict__ rel_bias,
                                            const int* __restrict__ rel_coords,
                                            const int* __restrict__ mask,
                                            u16* __restrict__ xbh, u16* __restrict__ xbl,
                                            u16* __restrict__ wbh, u16* __restrict__ wbl,
                                            u16* __restrict__ pfh, u16* __restrict__ pfl,
                                            float* __restrict__ bm) {
    int idx = blockIdx.x * 256 + threadIdx.x;
    if (idx < X4) {
        float4 v = ((const float4*)x)[idx];
        ushort4 h, l;
        h.x = f2bf(v.x); l.x = f2bf(v.x - bf2f(h.x));
        h.y = f2bf(v.y); l.y = f2bf(v.y - bf2f(h.y));
        h.z = f2bf(v.z); l.z = f2bf(v.z - bf2f(h.z));
        h.w = f2bf(v.w); l.w = f2bf(v.w - bf2f(h.w));
        ((ushort4*)xbh)[idx] = h;
        ((ushort4*)xbl)[idx] = l;
    } else if (idx < X4 + W4) {
        int i = idx - X4;
        float4 v = ((const float4*)qkv_w)[i];
        ushort4 h, l;
        h.x = f2bf(v.x); l.x = f2bf(v.x - bf2f(h.x));
        h.y = f2bf(v.y); l.y = f2bf(v.y - bf2f(h.y));
        h.z = f2bf(v.z); l.z = f2bf(v.z - bf2f(h.z));
        h.w = f2bf(v.w); l.w = f2bf(v.w - bf2f(h.w));
        ((ushort4*)wbh)[i] = h;
        ((ushort4*)wbl)[i] = l;
    } else if (idx < X4 + W4 + P4) {
        int i = idx - (X4 + W4);
        float4 v = ((const float4*)proj_w)[i];
        ushort4 h, l;
        h.x = f2h_bits(v.x); l.x = f2h_bits(v.x - (float)(_Float16)v.x);
        h.y = f2h_bits(v.y); l.y = f2h_bits(v.y - (float)(_Float16)v.y);
        h.z = f2h_bits(v.z); l.z = f2h_bits(v.z - (float)(_Float16)v.z);
        h.w = f2h_bits(v.w); l.w = f2h_bits(v.w - (float)(_Float16)v.w);
        ((ushort4*)pfh)[i] = h;
        ((ushort4*)pfl)[i] = l;
    } else if (idx < X4 + W4 + P4 + BM4) {
        int t = idx - (X4 + W4 + P4);
        float4 o;
        float* op = (float*)&o;
#pragma unroll
        for (int i = 0; i < 4; ++i) {
            int j = t * 4 + i;                 // bm flat index
            int e = j & 63;
            int col = (e & 3) * 16 + (e >> 2); // tn*16 + lc
            int row = (j >> 6) & 63;
            int wh_ = j >> 12;                 // 0..47
            int w = wh_ / NH;
            int h = wh_ - w * NH;
            float val = -1.0e30f;
            if (row < LW && col < LW) {
                int ij = row * LW + col;
                val = mask[w * (LW * LW) + ij] ? -1.0e4f
                                               : rel_bias[rel_coords[ij] * NH + h];
            }
            op[i] = val;
        }
        ((float4*)bm)[t] = o;
    }
}

// ---------------------------------------------------------------------------
// QKV GEMM (split-bf16): r9 structure (512 thr, 8 waves 64x32, 2-deep dbuf,
// counted vmcnt) + LDS XOR slot-swizzle: stage fetches global slot
// (slot ^ row&3) into linear LDS; reads XOR the slot back. 8-way -> 4-way
// bank conflict on ds_read_b128. XCD-chunked grid, n-tile innermost.
// ---------------------------------------------------------------------------
__global__ __launch_bounds__(512) void qkv_gemm(const u16* __restrict__ Ah,
                                                const u16* __restrict__ Al,
                                                const u16* __restrict__ Wh,
                                                const u16* __restrict__ Wl,
                                                u32* __restrict__ qp,
                                                u32* __restrict__ kp,
                                                u16* __restrict__ vp) {
    __shared__ u16 As_h[2][128 * 32];
    __shared__ u16 As_l[2][128 * 32];
    __shared__ u16 Bs_h[2][128 * 32];
    __shared__ u16 Bs_l[2][128 * 32];
    const int tid = threadIdx.x;
    const int w = tid >> 6;            // 0..7
    const int lane = tid & 63;
    // grid = 3528 = 441*8; XCD-chunked bijection, n-tile innermost
    const int bid = blockIdx.x;
    const int logical = (bid & 7) * 441 + (bid >> 3);
    const int mt = logical / 9;
    const int nt = logical - mt * 9;
    const int m0 = mt * 128;
    const int n0 = nt * 128;
    const bool vblk = (nt >= 6);
    const int quad = lane >> 4;
    const int lc = lane & 15;
    const int wrow = (w >> 2) << 6;    // 0 or 64
    const int wcol = (w & 3) << 5;     // 0,32,64,96
    const int srow = lane >> 2;
    // XOR-swizzled source slot: LDS (row, slot) holds global (row, slot^(row&3))
    const int sch = (((lane & 3) ^ (srow & 3))) * 8;
    // read-side slot XOR: fragment (row, quad) lives at slot quad^(row&3); row&3 == lc&3
    const int sl = ((lc & 3)) * 8;     // XOR applied per-read below via quad^

    floatx4 acc[4][2];
#pragma unroll
    for (int a = 0; a < 4; ++a)
#pragma unroll
        for (int b = 0; b < 2; ++b) acc[a][b] = (floatx4){0.f, 0.f, 0.f, 0.f};

    auto stage = [&](int buf, int k0) {   // q/k: 4 loads/wave; v: 2
        const int rb = w * 16;
        const size_t ga = (size_t)(m0 + rb + srow) * CD + k0 + sch;
        const size_t gb = (size_t)(n0 + rb + srow) * CD + k0 + sch;
        const int lof = rb * 32;
        gl_lds16(Ah + ga, As_h[buf] + lof);
        gl_lds16(Wh + gb, Bs_h[buf] + lof);
        if (!vblk) {
            gl_lds16(Al + ga, As_l[buf] + lof);
            gl_lds16(Wl + gb, Bs_l[buf] + lof);
        }
    };

    auto rd = [&](const u16* base_, int row) -> short8 {
        return *(const short8*)(base_ + row * 32 + ((quad ^ (row & 3)) * 8));
    };

    auto compute = [&](int buf) {
        if (!vblk) {
            short8 af_h[4], af_l[4], bf_h[2], bf_l[2];
#pragma unroll
            for (int t = 0; t < 4; ++t) {
                const int ar = wrow + t * 16 + lc;
                af_h[t] = rd(As_h[buf], ar);
                af_l[t] = rd(As_l[buf], ar);
            }
#pragma unroll
            for (int u = 0; u < 2; ++u) {
                const int br = wcol + u * 16 + lc;
                bf_h[u] = rd(Bs_h[buf], br);
                bf_l[u] = rd(Bs_l[buf], br);
            }
#pragma unroll
            for (int tm = 0; tm < 4; ++tm)
#pragma unroll
                for (int tn = 0; tn < 2; ++tn) {
                    acc[tm][tn] = __builtin_amdgcn_mfma_f32_16x16x32_bf16(af_h[tm], bf_h[tn], acc[tm][tn], 0, 0, 0);
                    acc[tm][tn] = __builtin_amdgcn_mfma_f32_16x16x32_bf16(af_h[tm], bf_l[tn], acc[tm][tn], 0, 0, 0);
                    acc[tm][tn] = __builtin_amdgcn_mfma_f32_16x16x32_bf16(af_l[tm], bf_h[tn], acc[tm][tn], 0, 0, 0);
                }
        } else {
            short8 af_h[4], bf_h[2];
#pragma unroll
            for (int t = 0; t < 4; ++t)
                af_h[t] = rd(As_h[buf], wrow + t * 16 + lc);
#pragma unroll
            for (int u = 0; u < 2; ++u)
                bf_h[u] = rd(Bs_h[buf], wcol + u * 16 + lc);
#pragma unroll
            for (int tm = 0; tm < 4; ++tm)
#pragma unroll
                for (int tn = 0; tn < 2; ++tn)
                    acc[tm][tn] = __builtin_amdgcn_mfma_f32_16x16x32_bf16(af_h[tm], bf_h[tn], acc[tm][tn], 0, 0, 0);
        }
    };

    stage(0, 0);
    stage(1, 32);
    if (!vblk) {
#pragma unroll
        for (int t = 0; t < 12; t += 2) {
            ASM_VMCNT(4); BAR();
            compute(0);
            ASM_LGKM0(); BAR();
            if (t + 2 < 12) { stage(0, (t + 2) * 32); ASM_VMCNT(4); }
            else            { ASM_VMCNT(0); }
            BAR();
            compute(1);
            ASM_LGKM0(); BAR();
            if (t + 2 < 12) stage(1, (t + 3) * 32);
        }
    } else {
#pragma unroll
        for (int t = 0; t < 12; t += 2) {
            ASM_VMCNT(2); BAR();
            compute(0);
            ASM_LGKM0(); BAR();
            if (t + 2 < 12) { stage(0, (t + 2) * 32); ASM_VMCNT(2); }
            else            { ASM_VMCNT(0); }
            BAR();
            compute(1);
            ASM_LGKM0(); BAR();
            if (t + 2 < 12) stage(1, (t + 3) * 32);
        }
    }
    (void)sl;

    // epilogue: D col = lane&15, row = quad*4 + reg
#pragma unroll
    for (int tn = 0; tn < 2; ++tn) {
        const int nst = n0 + wcol + tn * 16;
        const int t = nst / CD;
        const int rem = nst - t * CD;
        const int h = rem >> 5;
        const int db = (rem & 31) + lc;
#pragma unroll
        for (int tm = 0; tm < 4; ++tm)
#pragma unroll
            for (int r = 0; r < 4; ++r) {
                const int m = m0 + wrow + tm * 16 + quad * 4 + r;
                const int b = m / LW;
                const int l = m - b * LW;
                const size_t o = ((((size_t)b * NH + h) * LW + l) << 5) + db;
                const float vv = acc[tm][tn][r];
                if (t == 2) {
                    vp[o] = f2h_bits(vv);
                } else {
                    const unsigned bits = __float_as_uint(vv);
                    const unsigned hi_high = bits & 0xffff0000u;
                    const u16 lo = f2bf(vv - __uint_as_float(hi_high));
                    const u32 packed = hi_high | (u32)lo;
                    if (t == 0) qp[o] = packed; else kp[o] = packed;
                }
            }
    }
}

// ---------------------------------------------------------------------------
// Proj GEMM (f16 2-term): r9 structure (512 thr) + same LDS XOR slot-swizzle.
// out[m][n] = sum_k A[m][k]*(Wh+Wl)[n][k] + pb[n].
// ---------------------------------------------------------------------------
__global__ __launch_bounds__(512) void proj_gemm(const u16* __restrict__ Af,
                                                 const u16* __restrict__ Wfh,
                                                 const u16* __restrict__ Wfl,
                                                 const float* __restrict__ pb,
                                                 float* __restrict__ outF) {
    __shared__ u16 As_f[2][128 * 32];
    __shared__ u16 Bs_h[2][128 * 32];
    __shared__ u16 Bs_l[2][128 * 32];
    const int tid = threadIdx.x;
    const int w = tid >> 6;
    const int lane = tid & 63;
    // grid = 1176 = 147*8; XCD-chunked bijection, n-tile innermost
    const int bid = blockIdx.x;
    const int logical = (bid & 7) * 147 + (bid >> 3);
    const int mt = logical / 3;
    const int nt = logical - mt * 3;
    const int m0 = mt * 128;
    const int n0 = nt * 128;
    const int quad = lane >> 4;
    const int lc = lane & 15;
    const int wrow = (w >> 2) << 6;
    const int wcol = (w & 3) << 5;
    const int srow = lane >> 2;
    const int sch = (((lane & 3) ^ (srow & 3))) * 8;

    floatx4 acc[4][2];
#pragma unroll
    for (int a = 0; a < 4; ++a)
#pragma unroll
        for (int b = 0; b < 2; ++b) acc[a][b] = (floatx4){0.f, 0.f, 0.f, 0.f};

    auto stage = [&](int buf, int k0) {   // 3 loads/wave
        const int rb = w * 16;
        const size_t ga = (size_t)(m0 + rb + srow) * CD + k0 + sch;
        const size_t gb = (size_t)(n0 + rb + srow) * CD + k0 + sch;
        const int lof = rb * 32;
        gl_lds16(Af + ga, As_f[buf] + lof);
        gl_lds16(Wfh + gb, Bs_h[buf] + lof);
        gl_lds16(Wfl + gb, Bs_l[buf] + lof);
    };

    auto rd = [&](const u16* base_, int row) -> half8 {
        return *(const half8*)(base_ + row * 32 + ((quad ^ (row & 3)) * 8));
    };

    auto compute = [&](int buf) {
        half8 af[4], bh[2], bl[2];
#pragma unroll
        for (int t = 0; t < 4; ++t)
            af[t] = rd(As_f[buf], wrow + t * 16 + lc);
#pragma unroll
        for (int u = 0; u < 2; ++u) {
            const int br = wcol + u * 16 + lc;
            bh[u] = rd(Bs_h[buf], br);
            bl[u] = rd(Bs_l[buf], br);
        }
#pragma unroll
        for (int tm = 0; tm < 4; ++tm)
#pragma unroll
            for (int tn = 0; tn < 2; ++tn) {
                acc[tm][tn] = __builtin_amdgcn_mfma_f32_16x16x32_f16(af[tm], bh[tn], acc[tm][tn], 0, 0, 0);
                acc[tm][tn] = __builtin_amdgcn_mfma_f32_16x16x32_f16(af[tm], bl[tn], acc[tm][tn], 0, 0, 0);
            }
    };

    stage(0, 0);
    stage(1, 32);
#pragma unroll
    for (int t = 0; t < 12; t += 2) {
        ASM_VMCNT(3); BAR();
        compute(0);
        ASM_LGKM0(); BAR();
        if (t + 2 < 12) { stage(0, (t + 2) * 32); ASM_VMCNT(3); }
        else            { ASM_VMCNT(0); }
        BAR();
        compute(1);
        ASM_LGKM0(); BAR();
        if (t + 2 < 12) stage(1, (t + 3) * 32);
    }

#pragma unroll
    for (int tn = 0; tn < 2; ++tn) {
        const int n = n0 + wcol + tn * 16 + lc;
        const float bias = pb[n];
#pragma unroll
        for (int tm = 0; tm < 4; ++tm)
#pragma unroll
            for (int r = 0; r < 4; ++r) {
                const int m = m0 + wrow + tm * 16 + quad * 4 + r;
                outF[(size_t)m * CD + n] = acc[tm][tn][r] + bias;
            }
    }
}

// ---------------------------------------------------------------------------
// MFMA attention: 4 WAVES per (b,h) block (256 thr) — wave w owns tm=w:
// 1 q-tile, all 4 k-tiles, 12 QK^T MFMAs, 4 softmax rows, 4 PV MFMAs.
// Critical path /4 vs 1-wave version; shuffle-reduces are 16-lane-group
// local so they survive the split verbatim. Deferred 1/sum as before.
// ---------------------------------------------------------------------------
__global__ __launch_bounds__(256) void attn_mfma(const u32* __restrict__ qp,
                                                 const u32* __restrict__ kp,
                                                 const u16* __restrict__ vh,
                                                 const float* __restrict__ bm,
                                                 u16* __restrict__ aof) {
    const int bh = blockIdx.x;
    const int b = bh / NH;
    const int h = bh - b * NH;
    const int tid = threadIdx.x;
    const int w = tid >> 6;          // tm = w
    const int lane = tid & 63;
    const int quad = lane >> 4;
    const int lc = lane & 15;
    __shared__ u16 Vt[32 * 72];
    __shared__ u16 Ps[64 * 72];

    const size_t base = (size_t)bh * (LW * HD);

    // own q tile
    short8 aQh, aQl;
    {
        int row = w * 16 + lc; if (row > 48) row = 48;
        const size_t o = base + (size_t)row * HD + quad * 8;
        uint4 q0 = *(const uint4*)(qp + o);
        uint4 q1 = *(const uint4*)(qp + o + 4);
        unsigned qv[8] = {q0.x, q0.y, q0.z, q0.w, q1.x, q1.y, q1.z, q1.w};
#pragma unroll
        for (int e = 0; e < 8; ++e) {
            aQh[e] = (short)(qv[e] >> 16);
            aQl[e] = (short)(qv[e] & 0xffffu);
        }
    }
    // all 4 k tiles
    short8 bKh[4], bKl[4];
#pragma unroll
    for (int t = 0; t < 4; ++t) {
        int row = t * 16 + lc; if (row > 48) row = 48;
        const size_t o = base + (size_t)row * HD + quad * 8;
        uint4 k0 = *(const uint4*)(kp + o);
        uint4 k1 = *(const uint4*)(kp + o + 4);
        unsigned kv[8] = {k0.x, k0.y, k0.z, k0.w, k1.x, k1.y, k1.z, k1.w};
#pragma unroll
        for (int e = 0; e < 8; ++e) {
            bKh[t][e] = (short)(kv[e] >> 16);
            bKl[t][e] = (short)(kv[e] & 0xffffu);
        }
    }
    // stage V^T (f16): wave w stages its quarter (j in [w*16, w*16+16))
    {
        const int idx = lane + w * 64;
        const int j = idx >> 2;
        const int jc = j > 48 ? 48 : j;
        const int ch = (idx & 3) * 8;
        short8 vv = *(const short8*)(vh + base + (size_t)jc * HD + ch);
#pragma unroll
        for (int e = 0; e < 8; ++e) Vt[(ch + e) * 72 + j] = (u16)vv[e];
    }

    // QK^T for own 16 rows x all 64 cols
    floatx4 acc[4];
#pragma unroll
    for (int c = 0; c < 4; ++c) acc[c] = (floatx4){0.f, 0.f, 0.f, 0.f};
#pragma unroll
    for (int tn = 0; tn < 4; ++tn) {
        acc[tn] = __builtin_amdgcn_mfma_f32_16x16x32_bf16(aQh, bKh[tn], acc[tn], 0, 0, 0);
        acc[tn] = __builtin_amdgcn_mfma_f32_16x16x32_bf16(aQh, bKl[tn], acc[tn], 0, 0, 0);
        acc[tn] = __builtin_amdgcn_mfma_f32_16x16x32_bf16(aQl, bKh[tn], acc[tn], 0, 0, 0);
    }

    float inv_a[4];
    const float* bmp = bm + (((size_t)(b & 3) * NH + h) << 12);
#pragma unroll
    for (int r = 0; r < 4; ++r) {
        const int row = w * 16 + quad * 4 + r;
        const float4 bv = *(const float4*)(bmp + row * 64 + lc * 4);
        const float s0 = fmaf(acc[0][r], SCALE_F, bv.x);
        const float s1 = fmaf(acc[1][r], SCALE_F, bv.y);
        const float s2 = fmaf(acc[2][r], SCALE_F, bv.z);
        const float s3 = fmaf(acc[3][r], SCALE_F, bv.w);
        float mx = fmaxf(fmaxf(s0, s1), fmaxf(s2, s3));
#pragma unroll
        for (int off = 1; off < 16; off <<= 1) mx = fmaxf(mx, __shfl_xor(mx, off));
        const float e0 = __expf(s0 - mx);
        const float e1 = __expf(s1 - mx);
        const float e2 = __expf(s2 - mx);
        const float e3 = __expf(s3 - mx);
        float sum = (e0 + e1) + (e2 + e3);
#pragma unroll
        for (int off = 1; off < 16; off <<= 1) sum += __shfl_xor(sum, off);
        inv_a[r] = __builtin_amdgcn_rcpf(sum);
        Ps[row * 72 +  0 + lc] = f2h_bits(e0);
        Ps[row * 72 + 16 + lc] = f2h_bits(e1);
        Ps[row * 72 + 32 + lc] = f2h_bits(e2);
        Ps[row * 72 + 48 + lc] = f2h_bits(e3);
    }

    __syncthreads();

    // PV for own 16 rows
    floatx4 o0 = (floatx4){0.f, 0.f, 0.f, 0.f};
    floatx4 o1 = (floatx4){0.f, 0.f, 0.f, 0.f};
#pragma unroll
    for (int ks = 0; ks < 2; ++ks) {
        const half8 bV0 = *(const half8*)(Vt + (lc) * 72 + ks * 32 + quad * 8);
        const half8 bV1 = *(const half8*)(Vt + (16 + lc) * 72 + ks * 32 + quad * 8);
        const half8 aP = *(const half8*)(Ps + (w * 16 + lc) * 72 + ks * 32 + quad * 8);
        o0 = __builtin_amdgcn_mfma_f32_16x16x32_f16(aP, bV0, o0, 0, 0, 0);
        o1 = __builtin_amdgcn_mfma_f32_16x16x32_f16(aP, bV1, o1, 0, 0, 0);
    }
#pragma unroll
    for (int r = 0; r < 4; ++r) {
        const int i = w * 16 + quad * 4 + r;
        if (i < LW) {
            const float inv = inv_a[r];
            const size_t mm = ((size_t)b * LW + i) * CD + h * HD + lc;
            aof[mm] = f2h_bits(o0[r] * inv);
            aof[mm + 16] = f2h_bits(o1[r] * inv);
        }
    }
}

// ---------------------------------------------------------------------------
extern "C" void kernel_launch(void* const* d_in, const int* in_sizes, int n_in,
                              void* d_out, int out_size, void* d_ws, size_t ws_size,
                              hipStream_t stream) {
    const float* x          = (const float*)d_in[0];
    const int*   mask       = (const int*)d_in[1];
    const float* qkv_w      = (const float*)d_in[2];
    const float* proj_w     = (const float*)d_in[3];
    const float* proj_b     = (const float*)d_in[4];
    const float* rel_bias   = (const float*)d_in[5];
    const int*   rel_coords = (const int*)d_in[6];
    float* out = (float*)d_out;

    const size_t S = (size_t)NUM_B * NH * LW * HD;   // 19,267,584
    // ws (u16 units): xbh S | xbl S | kp 2S | vh S | wbh/wbl | pfh/pfl | bm
    u16* xbh = (u16*)d_ws;
    u16* xbl = xbh + S;
    u32* kp  = (u32*)(xbl + S);           // S u32
    u16* vh  = (u16*)(kp + S);            // S u16
    u16* wbh = vh + S;                    // 442368
    u16* wbl = wbh + 442368;
    u16* pfh = wbl + 442368;              // 147456
    u16* pfl = pfh + 147456;
    float* bm = (float*)(pfl + 147456);   // 196608 floats
    // q packed lives in d_out (S u32 == out_size f32); dead before proj writes
    u32* qp = (u32*)d_out;
    // attn f16 output reuses xbh (x dead after qkv_gemm)
    u16* aof = xbh;

    prep<<<dim3(19584), dim3(256), 0, stream>>>(x, qkv_w, proj_w, rel_bias, rel_coords,
                                                mask, xbh, xbl, wbh, wbl, pfh, pfl, bm);
    qkv_gemm<<<dim3(3528), dim3(512), 0, stream>>>(xbh, xbl, wbh, wbl, qp, kp, vh);
    attn_mfma<<<dim3(NUM_B * NH), dim3(256), 0, stream>>>(qp, kp, vh, bm, aof);
    proj_gemm<<<dim3(1176), dim3(512), 0, stream>>>(aof, pfh, pfl, proj_b, out);
}